// Round 3
// baseline (1289.424 us; speedup 1.0000x reference)
//
#include <hip/hip_runtime.h>

// AdaCoFNet forward on gfx950 — round 3.
// Convs: implicit-GEMM, 128oc x 256px(8x32) x 32ic tiles, 256-thr blocks,
// 2 independent blocks/CU (64 KB LDS each), 9-phase dbuf pipeline with
// counted vmcnt, 32x32x16 bf16 MFMA. Activations: padded NHWC bf16.
// Sampling: NHWC4 fp32 frames, float4 bilinear gathers.

static constexpr int HW  = 65536;  // 256*256
static constexpr int WID = 256;
static constexpr int PAD = 66564;  // 258*258

using f32x16 = __attribute__((ext_vector_type(16))) float;
using f32x4  = __attribute__((ext_vector_type(4))) float;
using s16x8  = __attribute__((ext_vector_type(8))) short;

__device__ __forceinline__ unsigned short f2b(float f) {
    unsigned u = __builtin_bit_cast(unsigned, f);
    u += 0x7fffu + ((u >> 16) & 1u);          // RNE
    return (unsigned short)(u >> 16);
}
__device__ __forceinline__ float b2f(unsigned short h) {
    unsigned u = ((unsigned)h) << 16;
    return __builtin_bit_cast(float, u);
}

template <int N> __device__ __forceinline__ void vm_wait() {
    asm volatile("s_waitcnt vmcnt(%0)" :: "n"(N) : "memory");
}

// ---------------------------------------------------------------- pack_x ---
__global__ void pack_x(const float* __restrict__ feat1, const float* __restrict__ feat2,
                       const float* __restrict__ corr, unsigned short* __restrict__ Xc) {
    int idx = blockIdx.x * 256 + threadIdx.x;   // 20 groups * 2*HW pixels
    int g  = idx >> 17;
    int bp = idx & (2 * HW - 1);
    int b  = bp >> 16, p = bp & 65535;
    unsigned short v[8];
#pragma unroll
    for (int j = 0; j < 8; ++j) {
        int c = g * 8 + j;
        float val = 0.f;
        if (c < 32)       val = feat1[(size_t)(b * 32 + c) * HW + p];
        else if (c < 64)  val = feat2[(size_t)(b * 32 + (c - 32)) * HW + p];
        else if (c < 145) val = corr [(size_t)(b * 81 + (c - 64)) * HW + p];
        v[j] = f2b(val);
    }
    uint4 u;
    u.x = v[0] | ((unsigned)v[1] << 16);
    u.y = v[2] | ((unsigned)v[3] << 16);
    u.z = v[4] | ((unsigned)v[5] << 16);
    u.w = v[6] | ((unsigned)v[7] << 16);
    int y = p >> 8, x = p & 255;
    size_t cell = (size_t)b * PAD + (size_t)(y + 1) * 258 + (x + 1);
    *reinterpret_cast<uint4*>(Xc + cell * 160 + g * 8) = u;
}

// ---------------------------------------------------------------- pack_w ---
// W[OC][IC][3][3] fp32 -> granule-major bf16: Wp[((s*KC+kb)*4+g)*OCP + oc][8ic]
__global__ void pack_w(const float* __restrict__ W, unsigned short* __restrict__ Wp,
                       int OC, int IC, int OCP, int KC) {
    int idx = blockIdx.x * 256 + threadIdx.x;
    int total = 9 * KC * 4 * OCP * 8;
    if (idx >= total) return;
    int i8 = idx & 7;  int r = idx >> 3;
    int oc = r % OCP;  r /= OCP;
    int g  = r & 3;    r >>= 2;
    int kb = r % KC;   int s = r / KC;
    int ic = kb * 32 + g * 8 + i8;
    float v = (oc < OC && ic < IC) ? W[((size_t)(oc * IC + ic)) * 9 + s] : 0.f;
    Wp[idx] = f2b(v);
}

// ----------------------------------------------------------- zero_border ---
__global__ void zero_border(unsigned short* __restrict__ buf, int C) {
    int idx = blockIdx.x * 256 + threadIdx.x;
    int G = C >> 3;
    int total = 2 * 1028 * G;
    if (idx >= total) return;
    int gi = idx % G; int r = idx / G;
    int ci = r % 1028; int b = r / 1028;
    int row, col;
    if (ci < 258)      { row = 0;            col = ci; }
    else if (ci < 516) { row = 257;          col = ci - 258; }
    else if (ci < 772) { row = ci - 516 + 1; col = 0; }
    else               { row = ci - 772 + 1; col = 257; }
    *reinterpret_cast<uint4*>(buf + ((size_t)b * PAD + row * 258 + col) * C + gi * 8) =
        make_uint4(0u, 0u, 0u, 0u);
}

// ----------------------------------------------------------------- conv3x3 -
// Block: 256 thr = 4 waves (wn 0..3). Tile: 128 oc x 256 px (8 rows x 32 cols);
// blockIdx.y selects the 128-oc slice. Wave: 128 oc x 64 px, acc[4][2] f32x16.
// LDS 64 KB: X dbuf 2x1536 granules, W dbuf 2x512 granules -> 2 blocks/CU.
// MODE 0: +bias, lrelu, bf16 padded NHWC store. MODE 1: +bias, fp32 NCHW.
template <int ICP, int OCF, int OCT, int MODE>
__global__ __launch_bounds__(256, 2) void conv3x3(
    const unsigned short* __restrict__ X,
    const uint4* __restrict__ Wp,
    const float* __restrict__ bias,
    unsigned short* __restrict__ outB,
    float* __restrict__ outF)
{
    constexpr int NT  = 256;
    constexpr int KC  = ICP / 32;
    constexpr int XGR = 1536;
    constexpr int WGR = 512;              // 4 g x 128 oc granules
    constexpr int XIT = XGR / NT;         // 6
    __shared__ uint4 lds[2 * XGR + 2 * WGR];   // 65536 B

    const int t = threadIdx.x;
    const int lane = t & 63, wn = t >> 6;
    const int l31 = lane & 31, hi = lane >> 5;
    const int ocOff = blockIdx.y * 128;

    const int bid  = blockIdx.x;                      // 512
    const int work = ((bid & 7) << 6) | (bid >> 3);   // XCD-bijective swizzle
    const int bb = work >> 8;
    const int tt = work & 255;
    const int tr = tt >> 3, tc = tt & 7;

    auto stage_x = [&](int kb, int slot) {
#pragma unroll
        for (int it = 0; it < XIT; ++it) {
            int G = it * NT + t;
            int g = G / 384;
            int cell = G - g * 384;
            cell = min(cell, 339);
            int rr = cell / 34, cc = cell - rr * 34;
            const unsigned short* src = X +
                ((size_t)bb * PAD + (size_t)(tr * 8 + rr) * 258 + tc * 32 + cc) * ICP +
                kb * 32 + g * 8;
            __builtin_amdgcn_global_load_lds(
                (const __attribute__((address_space(1))) unsigned int*)src,
                (__attribute__((address_space(3))) unsigned int*)&lds[slot * XGR + it * NT + (t & ~63)],
                16, 0, 0);
        }
    };
    auto stage_w = [&](int s, int kb, int slot) {
#pragma unroll
        for (int it = 0; it < 2; ++it) {
            int G = it * NT + t;                 // 0..511
            int g = G >> 7, oc = G & 127;
            const uint4* src = Wp + ((size_t)(s * KC + kb) * 4 + g) * OCF + ocOff + oc;
            __builtin_amdgcn_global_load_lds(
                (const __attribute__((address_space(1))) unsigned int*)src,
                (__attribute__((address_space(3))) unsigned int*)&lds[2 * XGR + slot * WGR + it * NT + (t & ~63)],
                16, 0, 0);
        }
    };

    f32x16 acc[4][2] = {};

    stage_x(0, 0);
    stage_w(0, 0, 0);
    vm_wait<0>();
    __builtin_amdgcn_s_barrier();

    int ph = 0;
    for (int kb = 0; kb < KC; ++kb) {
        const int xb = (kb & 1) * XGR;
#pragma unroll
        for (int s = 0; s < 9; ++s) {
            const int wcur = 2 * XGR + (ph & 1) * WGR;
            const bool lastPhase = (kb == KC - 1) && (s == 8);
            if (s < 8) {
                stage_w(s + 1, kb, (ph & 1) ^ 1);
            } else if (kb + 1 < KC) {
                stage_w(0, kb + 1, (ph & 1) ^ 1);
                stage_x(kb + 1, (kb & 1) ^ 1);
            }
            if (lastPhase)      vm_wait<0>();
            else if (s == 8)    vm_wait<2 + XIT>();
            else                vm_wait<2>();
            __builtin_amdgcn_s_barrier();

            const int dy = s / 3, dx = s - 3 * (s / 3);
            __builtin_amdgcn_s_setprio(1);
#pragma unroll
            for (int ks = 0; ks < 2; ++ks) {
                uint4 a[4], bq[2];
#pragma unroll
                for (int fm = 0; fm < 4; ++fm)
                    a[fm] = lds[wcur + (ks * 2 + hi) * 128 + fm * 32 + l31];
#pragma unroll
                for (int fn = 0; fn < 2; ++fn)
                    bq[fn] = lds[xb + (ks * 2 + hi) * 384 + (wn * 2 + fn + dy) * 34 + dx + l31];
#pragma unroll
                for (int fm = 0; fm < 4; ++fm)
#pragma unroll
                    for (int fn = 0; fn < 2; ++fn)
                        acc[fm][fn] = __builtin_amdgcn_mfma_f32_32x32x16_bf16(
                            __builtin_bit_cast(s16x8, a[fm]),
                            __builtin_bit_cast(s16x8, bq[fn]),
                            acc[fm][fn], 0, 0, 0);
            }
            __builtin_amdgcn_s_setprio(0);
            __builtin_amdgcn_s_barrier();
            ph ^= 1;
        }
    }

    // epilogue: D reg -> oc_rel = fm*32 + q*8 + hi*4 + j, px col = l31
#pragma unroll
    for (int fm = 0; fm < 4; ++fm) {
#pragma unroll
        for (int fn = 0; fn < 2; ++fn) {
            const int prow = wn * 2 + fn;
            if (MODE == 0) {
                const size_t cellp = (size_t)bb * PAD + (size_t)(tr * 8 + prow + 1) * 258 + tc * 32 + l31 + 1;
#pragma unroll
                for (int q = 0; q < 4; ++q) {
                    const int goc = ocOff + fm * 32 + q * 8 + hi * 4;
                    if (goc < OCT) {
                        float4 bv = *reinterpret_cast<const float4*>(bias + goc);
                        const float* bvp = reinterpret_cast<const float*>(&bv);
                        unsigned short o[4];
#pragma unroll
                        for (int j = 0; j < 4; ++j) {
                            float r = acc[fm][fn][q * 4 + j] + bvp[j];
                            r = (r >= 0.f) ? r : 0.1f * r;
                            o[j] = f2b(r);
                        }
                        uint2 pk;
                        pk.x = o[0] | ((unsigned)o[1] << 16);
                        pk.y = o[2] | ((unsigned)o[3] << 16);
                        *reinterpret_cast<uint2*>(outB + cellp * OCT + goc) = pk;
                    }
                }
            } else {
                const int py = tr * 8 + prow, px = tc * 32 + l31;
#pragma unroll
                for (int q = 0; q < 4; ++q) {
#pragma unroll
                    for (int j = 0; j < 4; ++j) {
                        const int oc = ocOff + fm * 32 + q * 8 + hi * 4 + j;
                        if (oc < OCT)
                            outF[((size_t)bb * OCT + oc) * HW + py * WID + px] =
                                acc[fm][fn][q * 4 + j] + bias[oc];
                    }
                }
            }
        }
    }
}

// -------------------------------------------------------------- softmax49 --
__global__ void softmax49(float* __restrict__ L) {
    int idx = blockIdx.x * 256 + threadIdx.x;   // 2*HW
    int b = idx >> 16, p = idx & 65535;
    float* lp = L + (size_t)b * 49 * HW + p;
    float v[49];
    float mx = -1e30f;
#pragma unroll
    for (int k = 0; k < 49; ++k) { v[k] = lp[(size_t)k * HW]; mx = fmaxf(mx, v[k]); }
    float sum = 0.f;
#pragma unroll
    for (int k = 0; k < 49; ++k) { v[k] = expf(v[k] - mx); sum += v[k]; }
    float inv = 1.f / sum;
#pragma unroll
    for (int k = 0; k < 49; ++k) lp[(size_t)k * HW] = v[k] * inv;
}

// ---------------------------------------------------------------- blend2 ---
__global__ void blend2k(const unsigned short* __restrict__ Fb, const float* __restrict__ W2,
                        const float* __restrict__ B2, float* __restrict__ blendOut) {
    int idx = blockIdx.x * 256 + threadIdx.x;   // 2*HW
    int b = idx >> 16, p = idx & 65535, y = p >> 8, x = p & 255;
    float acc = B2[0];
#pragma unroll
    for (int ry = 0; ry < 3; ++ry) {
#pragma unroll
        for (int rx = 0; rx < 3; ++rx) {
            const unsigned short* fp = Fb + ((size_t)b * PAD + (size_t)(y + ry) * 258 + (x + rx)) * 64;
#pragma unroll
            for (int g = 0; g < 8; ++g) {
                uint4 u = *reinterpret_cast<const uint4*>(fp + g * 8);
                unsigned w[4] = {u.x, u.y, u.z, u.w};
#pragma unroll
                for (int h = 0; h < 4; ++h) {
                    int c = g * 8 + h * 2;
                    acc += b2f((unsigned short)(w[h] & 0xffffu)) * W2[(c)     * 9 + ry * 3 + rx];
                    acc += b2f((unsigned short)(w[h] >> 16))     * W2[(c + 1) * 9 + ry * 3 + rx];
                }
            }
        }
    }
    blendOut[idx] = 1.f / (1.f + expf(-acc));
}

// ------------------------------------------------------------ pack_frames -
// frame[b][c][hw] fp32 NCHW -> Ff[fr*2+b][hw] float4 (c in .xyz, .w=0)
__global__ void pack_frames(const float* __restrict__ f1, const float* __restrict__ f2,
                            f32x4* __restrict__ Ff) {
    int idx = blockIdx.x * 256 + threadIdx.x;   // 2 frames * 2*HW
    int fr = idx >> 17; int bp = idx & (2 * HW - 1);
    const float* src = fr ? f2 : f1;
    int b = bp >> 16, p = bp & 65535;
    f32x4 v;
    v[0] = src[(size_t)(b * 3 + 0) * HW + p];
    v[1] = src[(size_t)(b * 3 + 1) * HW + p];
    v[2] = src[(size_t)(b * 3 + 2) * HW + p];
    v[3] = 0.f;
    Ff[(size_t)fr * 2 * HW + bp] = v;
}

// ------------------------------------------------------------- sampling ----
__device__ __forceinline__ void sample_accum4(const f32x4* __restrict__ img,
                                              const float* __restrict__ off,
                                              const float* __restrict__ wt,
                                              int x, int y, f32x4& s) {
    for (int k = 0; k < 49; ++k) {
        float dx = off[(size_t)(2 * k) * HW];
        float dy = off[(size_t)(2 * k + 1) * HW];
        float w  = wt [(size_t)k * HW];
        float px = ((float)x + dx) * (256.f / 255.f) - 0.5f;
        float py = ((float)y + dy) * (256.f / 255.f) - 0.5f;
        px = fminf(fmaxf(px, 0.f), 255.f);
        py = fminf(fmaxf(py, 0.f), 255.f);
        float x0f = floorf(px), y0f = floorf(py);
        float fx = px - x0f, fy = py - y0f;
        int x0 = (int)x0f, y0 = (int)y0f;
        int x1 = min(x0 + 1, 255), y1 = min(y0 + 1, 255);
        const f32x4* r0 = img + y0 * WID;
        const f32x4* r1 = img + y1 * WID;
        f32x4 v = (1.f - fy) * ((1.f - fx) * r0[x0] + fx * r0[x1]) +
                  fy         * ((1.f - fx) * r1[x0] + fx * r1[x1]);
        s += w * v;
    }
}

__global__ void sample_final(const f32x4* __restrict__ Ff,
                             const float* __restrict__ off1, const float* __restrict__ off2,
                             const float* __restrict__ wt1, const float* __restrict__ wt2,
                             const float* __restrict__ blend, float* __restrict__ out) {
    int idx = blockIdx.x * 256 + threadIdx.x;   // 2*HW
    int b = idx >> 16, p = idx & 65535, y = p >> 8, x = p & 255;
    f32x4 s1 = {0.f, 0.f, 0.f, 0.f}, s2 = {0.f, 0.f, 0.f, 0.f};
    sample_accum4(Ff + (size_t)b * HW, off1 + (size_t)b * 98 * HW + p,
                  wt1 + (size_t)b * 49 * HW + p, x, y, s1);
    sample_accum4(Ff + (size_t)(2 + b) * HW, off2 + (size_t)b * 98 * HW + p,
                  wt2 + (size_t)b * 49 * HW + p, x, y, s2);
    float bl = blend[idx];
#pragma unroll
    for (int c = 0; c < 3; ++c)
        out[(size_t)(b * 3 + c) * HW + p] = bl * s1[c] + (1.f - bl) * s2[c];
}

// ---------------------------------------------------------------------------
extern "C" void kernel_launch(void* const* d_in, const int* in_sizes, int n_in,
                              void* d_out, int out_size, void* d_ws, size_t ws_size,
                              hipStream_t stream) {
    (void)in_sizes; (void)n_in; (void)out_size; (void)ws_size;
    const float* frame1 = (const float*)d_in[0];
    const float* frame2 = (const float*)d_in[1];
    const float* feat1  = (const float*)d_in[2];
    const float* feat2  = (const float*)d_in[3];
    const float* corr   = (const float*)d_in[4];
    const float* Wsrc[2][5];
    const float* Bsrc[2][5];
    for (int pdx = 0; pdx < 2; ++pdx) {
        int base = 5 + pdx * 10;
        for (int l = 0; l < 5; ++l) {
            Wsrc[pdx][l] = (const float*)d_in[base + 2 * l];
            Bsrc[pdx][l] = (const float*)d_in[base + 2 * l + 1];
        }
    }
    const float* bl_w1 = (const float*)d_in[25];
    const float* bl_b1 = (const float*)d_in[26];
    const float* bl_w2 = (const float*)d_in[27];
    const float* bl_b2 = (const float*)d_in[28];

    float* out      = (float*)d_out;
    float* out_bl   = out + 393216;
    float* out_off[2] = {out + 524288,   out + 13369344};
    float* out_wt [2] = {out + 26214400, out + 32636928};

    // workspace carve (~186 MB)
    char* ws = (char*)d_ws;
    size_t o = 0;
    auto alloc = [&](size_t bytes) { char* p = ws + o; o += (bytes + 255) & ~(size_t)255; return p; };
    unsigned short* Xc   = (unsigned short*)alloc((size_t)2 * PAD * 160 * 2);
    unsigned short* bufA = (unsigned short*)alloc((size_t)2 * PAD * 256 * 2);
    unsigned short* bufB = (unsigned short*)alloc((size_t)2 * PAD * 256 * 2);
    unsigned short *WpC1[2], *WpC2[2], *WpC3[2], *WpCo[2], *WpCw[2];
    for (int pdx = 0; pdx < 2; ++pdx) {
        WpC1[pdx] = (unsigned short*)alloc((size_t)9 * 256 * 160 * 2);
        WpC2[pdx] = (unsigned short*)alloc((size_t)9 * 256 * 256 * 2);
        WpC3[pdx] = (unsigned short*)alloc((size_t)9 * 128 * 256 * 2);
        WpCo[pdx] = (unsigned short*)alloc((size_t)9 * 128 * 128 * 2);
        WpCw[pdx] = (unsigned short*)alloc((size_t)9 * 128 * 128 * 2);
    }
    unsigned short* WpBl = (unsigned short*)alloc((size_t)9 * 128 * 160 * 2);
    f32x4* Ff = (f32x4*)bufA;   // reuse: bufA dead before sampling stage

    auto packw = [&](const float* W, unsigned short* Wp, int OC, int IC, int OCP, int ICP) {
        int total = 9 * OCP * ICP;
        pack_w<<<(total + 255) / 256, 256, 0, stream>>>(W, Wp, OC, IC, OCP, ICP / 32);
    };
    auto zb = [&](unsigned short* buf, int C) {
        int total = 2 * 1028 * (C / 8);
        zero_border<<<(total + 255) / 256, 256, 0, stream>>>(buf, C);
    };

    // stage 0: packing + border zeroing
    zb(Xc, 160);
    pack_x<<<(2 * HW * 20) / 256, 256, 0, stream>>>(feat1, feat2, corr, Xc);
    for (int pdx = 0; pdx < 2; ++pdx) {
        packw(Wsrc[pdx][0], WpC1[pdx], 256, 145, 256, 160);
        packw(Wsrc[pdx][1], WpC2[pdx], 256, 256, 256, 256);
        packw(Wsrc[pdx][2], WpC3[pdx], 128, 256, 128, 256);
        packw(Wsrc[pdx][3], WpCo[pdx],  98, 128, 128, 128);
        packw(Wsrc[pdx][4], WpCw[pdx],  49, 128, 128, 128);
    }
    packw(bl_w1, WpBl, 64, 145, 128, 160);
    zb(bufB, 256);

    // stage 1: the two predictors
    for (int pdx = 0; pdx < 2; ++pdx) {
        zb(bufA, 256);
        conv3x3<160, 256, 256, 0><<<dim3(512, 2), 256, 0, stream>>>(
            Xc, (const uint4*)WpC1[pdx], Bsrc[pdx][0], bufA, nullptr);
        conv3x3<256, 256, 256, 0><<<dim3(512, 2), 256, 0, stream>>>(
            bufA, (const uint4*)WpC2[pdx], Bsrc[pdx][1], bufB, nullptr);
        zb(bufA, 128);
        conv3x3<256, 128, 128, 0><<<dim3(512, 1), 256, 0, stream>>>(
            bufB, (const uint4*)WpC3[pdx], Bsrc[pdx][2], bufA, nullptr);
        conv3x3<128, 128, 98, 1><<<dim3(512, 1), 256, 0, stream>>>(
            bufA, (const uint4*)WpCo[pdx], Bsrc[pdx][3], nullptr, out_off[pdx]);
        conv3x3<128, 128, 49, 1><<<dim3(512, 1), 256, 0, stream>>>(
            bufA, (const uint4*)WpCw[pdx], Bsrc[pdx][4], nullptr, out_wt[pdx]);
        softmax49<<<512, 256, 0, stream>>>(out_wt[pdx]);
    }

    // stage 2: blend mask (bufB free after pdx1 conv3)
    zb(bufB, 64);
    conv3x3<160, 128, 64, 0><<<dim3(512, 1), 256, 0, stream>>>(
        Xc, (const uint4*)WpBl, bl_b1, bufB, nullptr);
    blend2k<<<512, 256, 0, stream>>>(bufB, bl_w2, bl_b2, out_bl);

    // stage 3: frame pack + deformable sampling + final blend
    pack_frames<<<(4 * HW) / 256, 256, 0, stream>>>(frame1, frame2, Ff);
    sample_final<<<512, 256, 0, stream>>>(Ff, out_off[0], out_off[1],
                                          out_wt[0], out_wt[1], out_bl, out);
}

// Round 4
// 1214.201 us; speedup vs baseline: 1.0620x; 1.0620x over previous
//
#include <hip/hip_runtime.h>

// AdaCoFNet forward on gfx950 — round 4.
// Convs: implicit-GEMM, 128oc x 512px(16x32) x 32ic, 512-thr/8-wave blocks,
// 1 block/CU @ 128 KB LDS. Phase = one dy-group (3 shifts): 36 ds_read_b128 +
// 48 MFMA(32x32x16) between one barrier pair; W dy-group dbuf + X kb dbuf,
// counted vmcnt (3/8/0). Activations: padded NHWC bf16 [258][258][C].

static constexpr int HW  = 65536;  // 256*256
static constexpr int WID = 256;
static constexpr int PAD = 66564;  // 258*258

using f32x16 = __attribute__((ext_vector_type(16))) float;
using f32x4  = __attribute__((ext_vector_type(4))) float;
using s16x8  = __attribute__((ext_vector_type(8))) short;

__device__ __forceinline__ unsigned short f2b(float f) {
    unsigned u = __builtin_bit_cast(unsigned, f);
    u += 0x7fffu + ((u >> 16) & 1u);          // RNE
    return (unsigned short)(u >> 16);
}
__device__ __forceinline__ float b2f(unsigned short h) {
    unsigned u = ((unsigned)h) << 16;
    return __builtin_bit_cast(float, u);
}

template <int N> __device__ __forceinline__ void vm_wait() {
    asm volatile("s_waitcnt vmcnt(%0)" :: "n"(N) : "memory");
}

// ---------------------------------------------------------------- pack_x ---
__global__ void pack_x(const float* __restrict__ feat1, const float* __restrict__ feat2,
                       const float* __restrict__ corr, unsigned short* __restrict__ Xc) {
    int idx = blockIdx.x * 256 + threadIdx.x;   // 20 groups * 2*HW pixels
    int g  = idx >> 17;
    int bp = idx & (2 * HW - 1);
    int b  = bp >> 16, p = bp & 65535;
    unsigned short v[8];
#pragma unroll
    for (int j = 0; j < 8; ++j) {
        int c = g * 8 + j;
        float val = 0.f;
        if (c < 32)       val = feat1[(size_t)(b * 32 + c) * HW + p];
        else if (c < 64)  val = feat2[(size_t)(b * 32 + (c - 32)) * HW + p];
        else if (c < 145) val = corr [(size_t)(b * 81 + (c - 64)) * HW + p];
        v[j] = f2b(val);
    }
    uint4 u;
    u.x = v[0] | ((unsigned)v[1] << 16);
    u.y = v[2] | ((unsigned)v[3] << 16);
    u.z = v[4] | ((unsigned)v[5] << 16);
    u.w = v[6] | ((unsigned)v[7] << 16);
    int y = p >> 8, x = p & 255;
    size_t cell = (size_t)b * PAD + (size_t)(y + 1) * 258 + (x + 1);
    *reinterpret_cast<uint4*>(Xc + cell * 160 + g * 8) = u;
}

// ---------------------------------------------------------------- pack_w ---
// W[OC][IC][3][3] fp32 -> granule-major bf16: Wp[((s*KC+kb)*4+g)*OCP + oc][8ic]
__global__ void pack_w(const float* __restrict__ W, unsigned short* __restrict__ Wp,
                       int OC, int IC, int OCP, int KC) {
    int idx = blockIdx.x * 256 + threadIdx.x;
    int total = 9 * KC * 4 * OCP * 8;
    if (idx >= total) return;
    int i8 = idx & 7;  int r = idx >> 3;
    int oc = r % OCP;  r /= OCP;
    int g  = r & 3;    r >>= 2;
    int kb = r % KC;   int s = r / KC;
    int ic = kb * 32 + g * 8 + i8;
    float v = (oc < OC && ic < IC) ? W[((size_t)(oc * IC + ic)) * 9 + s] : 0.f;
    Wp[idx] = f2b(v);
}

// ----------------------------------------------------------- zero_border ---
__global__ void zero_border(unsigned short* __restrict__ buf, int C) {
    int idx = blockIdx.x * 256 + threadIdx.x;
    int G = C >> 3;
    int total = 2 * 1028 * G;
    if (idx >= total) return;
    int gi = idx % G; int r = idx / G;
    int ci = r % 1028; int b = r / 1028;
    int row, col;
    if (ci < 258)      { row = 0;            col = ci; }
    else if (ci < 516) { row = 257;          col = ci - 258; }
    else if (ci < 772) { row = ci - 516 + 1; col = 0; }
    else               { row = ci - 772 + 1; col = 257; }
    *reinterpret_cast<uint4*>(buf + ((size_t)b * PAD + row * 258 + col) * C + gi * 8) =
        make_uint4(0u, 0u, 0u, 0u);
}

// ----------------------------------------------------------------- conv3x3 -
// Block: 512 thr = 8 waves (wn 0..7). Tile: 128 oc x 512 px (16 rows x 32 cols);
// blockIdx.y = 128-oc slice. Wave: 128 oc x 64 px (2 rows), acc[4][2] f32x16.
// LDS 128 KB: X dbuf 2x2560 granules ([g:4][640 cells], cell=rr*34+cc, 18x34),
//             W dy-group dbuf 2x1536 ([dx:3][g:4][oc:128]).
// Phase = one dy (3 dx shifts): 36 ds_read_b128 + 48 MFMA per wave.
// MODE 0: +bias, lrelu, bf16 padded NHWC store. MODE 1: +bias, fp32 NCHW.
template <int ICP, int OCF, int OCT, int MODE>
__global__ __launch_bounds__(512, 2) void conv3x3(
    const unsigned short* __restrict__ X,
    const uint4* __restrict__ Wp,
    const float* __restrict__ bias,
    unsigned short* __restrict__ outB,
    float* __restrict__ outF)
{
    constexpr int KC = ICP / 32;
    __shared__ uint4 lds[8192];               // 131072 B

    const int t = threadIdx.x;
    const int lane = t & 63, wn = t >> 6;
    const int l31 = lane & 31, hi = lane >> 5;
    const int ocOff = blockIdx.y * 128;

    const int bid = blockIdx.x;               // 256 tiles (2 batches x 128)
    const int q8  = gridDim.x >> 3;
    const int work = (bid & 7) * q8 + (bid >> 3);   // XCD-bijective swizzle
    const int bb = work >> 7;
    const int tt = work & 127;
    const int tr = tt >> 3, tc = tt & 7;      // 16 row-tiles x 8 col-tiles

    auto stage_x = [&](int kb2, int slot) {
#pragma unroll
        for (int it = 0; it < 5; ++it) {
            int G = it * 512 + t;
            int g = G / 640;
            int cell = G - g * 640;
            cell = min(cell, 611);
            int rr = cell / 34, cc = cell - rr * 34;
            const unsigned short* src = X +
                ((size_t)bb * PAD + (size_t)(tr * 16 + rr) * 258 + tc * 32 + cc) * ICP +
                kb2 * 32 + g * 8;
            __builtin_amdgcn_global_load_lds(
                (const __attribute__((address_space(1))) unsigned int*)src,
                (__attribute__((address_space(3))) unsigned int*)&lds[slot * 2560 + it * 512 + (t & ~63)],
                16, 0, 0);
        }
    };
    auto stage_wg = [&](int kb2, int dy2, int wslot) {
#pragma unroll
        for (int j = 0; j < 3; ++j) {
            int s = dy2 * 3 + j;
            const uint4* src = Wp + ((size_t)(s * KC + kb2) * 4 + (t >> 7)) * OCF + ocOff + (t & 127);
            __builtin_amdgcn_global_load_lds(
                (const __attribute__((address_space(1))) unsigned int*)src,
                (__attribute__((address_space(3))) unsigned int*)&lds[5120 + wslot * 1536 + j * 512 + (t & ~63)],
                16, 0, 0);
        }
    };

    f32x16 acc[4][2] = {};

    stage_x(0, 0);
    stage_wg(0, 0, 0);

    int ph = 0;
#pragma unroll 1
    for (int kb = 0; kb < KC; ++kb) {
        const int xb = (kb & 1) * 2560;
#pragma unroll
        for (int dy = 0; dy < 3; ++dy) {
            const int wb = 5120 + (ph & 1) * 1536;
            if (dy < 2) {
                stage_wg(kb, dy + 1, (ph & 1) ^ 1);
                vm_wait<3>();
            } else if (kb + 1 < KC) {
                stage_wg(kb + 1, 0, (ph & 1) ^ 1);
                stage_x(kb + 1, (kb & 1) ^ 1);
                vm_wait<8>();
            } else {
                vm_wait<0>();
            }
            __builtin_amdgcn_s_barrier();

#pragma unroll
            for (int dxi = 0; dxi < 3; ++dxi) {
                uint4 a[2][4], bq[2][2];
#pragma unroll
                for (int ks = 0; ks < 2; ++ks) {
#pragma unroll
                    for (int fm = 0; fm < 4; ++fm)
                        a[ks][fm] = lds[wb + dxi * 512 + (ks * 2 + hi) * 128 + fm * 32 + l31];
#pragma unroll
                    for (int fn = 0; fn < 2; ++fn)
                        bq[ks][fn] = lds[xb + (ks * 2 + hi) * 640 + (wn * 2 + fn + dy) * 34 + dxi + l31];
                }
                __builtin_amdgcn_s_setprio(1);
#pragma unroll
                for (int ks = 0; ks < 2; ++ks)
#pragma unroll
                    for (int fm = 0; fm < 4; ++fm)
#pragma unroll
                        for (int fn = 0; fn < 2; ++fn)
                            acc[fm][fn] = __builtin_amdgcn_mfma_f32_32x32x16_bf16(
                                __builtin_bit_cast(s16x8, a[ks][fm]),
                                __builtin_bit_cast(s16x8, bq[ks][fn]),
                                acc[fm][fn], 0, 0, 0);
                __builtin_amdgcn_s_setprio(0);
            }
            __builtin_amdgcn_s_barrier();
            ph ^= 1;
        }
    }

    // epilogue: D reg -> oc_rel = fm*32 + q*8 + hi*4 + j, px col = l31
#pragma unroll
    for (int fm = 0; fm < 4; ++fm) {
#pragma unroll
        for (int fn = 0; fn < 2; ++fn) {
            const int prow = wn * 2 + fn;
            if (MODE == 0) {
                const size_t cellp = (size_t)bb * PAD + (size_t)(tr * 16 + prow + 1) * 258 + tc * 32 + l31 + 1;
#pragma unroll
                for (int qd = 0; qd < 4; ++qd) {
                    const int goc = ocOff + fm * 32 + qd * 8 + hi * 4;
                    if (goc < OCT) {
                        float4 bv = *reinterpret_cast<const float4*>(bias + goc);
                        const float* bvp = reinterpret_cast<const float*>(&bv);
                        unsigned short o[4];
#pragma unroll
                        for (int j = 0; j < 4; ++j) {
                            float r = acc[fm][fn][qd * 4 + j] + bvp[j];
                            r = (r >= 0.f) ? r : 0.1f * r;
                            o[j] = f2b(r);
                        }
                        uint2 pk;
                        pk.x = o[0] | ((unsigned)o[1] << 16);
                        pk.y = o[2] | ((unsigned)o[3] << 16);
                        *reinterpret_cast<uint2*>(outB + cellp * OCT + goc) = pk;
                    }
                }
            } else {
                const int py = tr * 16 + prow, px = tc * 32 + l31;
#pragma unroll
                for (int qd = 0; qd < 4; ++qd) {
#pragma unroll
                    for (int j = 0; j < 4; ++j) {
                        const int oc = ocOff + fm * 32 + qd * 8 + hi * 4 + j;
                        if (oc < OCT)
                            outF[((size_t)bb * OCT + oc) * HW + py * WID + px] =
                                acc[fm][fn][qd * 4 + j] + bias[oc];
                    }
                }
            }
        }
    }
}

// -------------------------------------------------------------- softmax49 --
__global__ void softmax49(float* __restrict__ L) {
    int idx = blockIdx.x * 256 + threadIdx.x;   // 2*HW
    int b = idx >> 16, p = idx & 65535;
    float* lp = L + (size_t)b * 49 * HW + p;
    float v[49];
    float mx = -1e30f;
#pragma unroll
    for (int k = 0; k < 49; ++k) { v[k] = lp[(size_t)k * HW]; mx = fmaxf(mx, v[k]); }
    float sum = 0.f;
#pragma unroll
    for (int k = 0; k < 49; ++k) { v[k] = expf(v[k] - mx); sum += v[k]; }
    float inv = 1.f / sum;
#pragma unroll
    for (int k = 0; k < 49; ++k) lp[(size_t)k * HW] = v[k] * inv;
}

// ---------------------------------------------------------------- blend2 ---
__global__ void blend2k(const unsigned short* __restrict__ Fb, const float* __restrict__ W2,
                        const float* __restrict__ B2, float* __restrict__ blendOut) {
    int idx = blockIdx.x * 256 + threadIdx.x;   // 2*HW
    int b = idx >> 16, p = idx & 65535, y = p >> 8, x = p & 255;
    float acc = B2[0];
#pragma unroll
    for (int ry = 0; ry < 3; ++ry) {
#pragma unroll
        for (int rx = 0; rx < 3; ++rx) {
            const unsigned short* fp = Fb + ((size_t)b * PAD + (size_t)(y + ry) * 258 + (x + rx)) * 64;
#pragma unroll
            for (int g = 0; g < 8; ++g) {
                uint4 u = *reinterpret_cast<const uint4*>(fp + g * 8);
                unsigned w[4] = {u.x, u.y, u.z, u.w};
#pragma unroll
                for (int h = 0; h < 4; ++h) {
                    int c = g * 8 + h * 2;
                    acc += b2f((unsigned short)(w[h] & 0xffffu)) * W2[(c)     * 9 + ry * 3 + rx];
                    acc += b2f((unsigned short)(w[h] >> 16))     * W2[(c + 1) * 9 + ry * 3 + rx];
                }
            }
        }
    }
    blendOut[idx] = 1.f / (1.f + expf(-acc));
}

// ------------------------------------------------------------ pack_frames -
__global__ void pack_frames(const float* __restrict__ f1, const float* __restrict__ f2,
                            f32x4* __restrict__ Ff) {
    int idx = blockIdx.x * 256 + threadIdx.x;   // 2 frames * 2*HW
    int fr = idx >> 17; int bp = idx & (2 * HW - 1);
    const float* src = fr ? f2 : f1;
    int b = bp >> 16, p = bp & 65535;
    f32x4 v;
    v[0] = src[(size_t)(b * 3 + 0) * HW + p];
    v[1] = src[(size_t)(b * 3 + 1) * HW + p];
    v[2] = src[(size_t)(b * 3 + 2) * HW + p];
    v[3] = 0.f;
    Ff[(size_t)fr * 2 * HW + bp] = v;
}

// ------------------------------------------------------------- sampling ----
__device__ __forceinline__ void sample_accum4(const f32x4* __restrict__ img,
                                              const float* __restrict__ off,
                                              const float* __restrict__ wt,
                                              int x, int y, f32x4& s) {
    for (int k = 0; k < 49; ++k) {
        float dx = off[(size_t)(2 * k) * HW];
        float dy = off[(size_t)(2 * k + 1) * HW];
        float w  = wt [(size_t)k * HW];
        float px = ((float)x + dx) * (256.f / 255.f) - 0.5f;
        float py = ((float)y + dy) * (256.f / 255.f) - 0.5f;
        px = fminf(fmaxf(px, 0.f), 255.f);
        py = fminf(fmaxf(py, 0.f), 255.f);
        float x0f = floorf(px), y0f = floorf(py);
        float fx = px - x0f, fy = py - y0f;
        int x0 = (int)x0f, y0 = (int)y0f;
        int x1 = min(x0 + 1, 255), y1 = min(y0 + 1, 255);
        const f32x4* r0 = img + y0 * WID;
        const f32x4* r1 = img + y1 * WID;
        f32x4 v = (1.f - fy) * ((1.f - fx) * r0[x0] + fx * r0[x1]) +
                  fy         * ((1.f - fx) * r1[x0] + fx * r1[x1]);
        s += w * v;
    }
}

__global__ void sample_final(const f32x4* __restrict__ Ff,
                             const float* __restrict__ off1, const float* __restrict__ off2,
                             const float* __restrict__ wt1, const float* __restrict__ wt2,
                             const float* __restrict__ blend, float* __restrict__ out) {
    int idx = blockIdx.x * 256 + threadIdx.x;   // 2*HW
    int b = idx >> 16, p = idx & 65535, y = p >> 8, x = p & 255;
    f32x4 s1 = {0.f, 0.f, 0.f, 0.f}, s2 = {0.f, 0.f, 0.f, 0.f};
    sample_accum4(Ff + (size_t)b * HW, off1 + (size_t)b * 98 * HW + p,
                  wt1 + (size_t)b * 49 * HW + p, x, y, s1);
    sample_accum4(Ff + (size_t)(2 + b) * HW, off2 + (size_t)b * 98 * HW + p,
                  wt2 + (size_t)b * 49 * HW + p, x, y, s2);
    float bl = blend[idx];
#pragma unroll
    for (int c = 0; c < 3; ++c)
        out[(size_t)(b * 3 + c) * HW + p] = bl * s1[c] + (1.f - bl) * s2[c];
}

// ---------------------------------------------------------------------------
extern "C" void kernel_launch(void* const* d_in, const int* in_sizes, int n_in,
                              void* d_out, int out_size, void* d_ws, size_t ws_size,
                              hipStream_t stream) {
    (void)in_sizes; (void)n_in; (void)out_size; (void)ws_size;
    const float* frame1 = (const float*)d_in[0];
    const float* frame2 = (const float*)d_in[1];
    const float* feat1  = (const float*)d_in[2];
    const float* feat2  = (const float*)d_in[3];
    const float* corr   = (const float*)d_in[4];
    const float* Wsrc[2][5];
    const float* Bsrc[2][5];
    for (int pdx = 0; pdx < 2; ++pdx) {
        int base = 5 + pdx * 10;
        for (int l = 0; l < 5; ++l) {
            Wsrc[pdx][l] = (const float*)d_in[base + 2 * l];
            Bsrc[pdx][l] = (const float*)d_in[base + 2 * l + 1];
        }
    }
    const float* bl_w1 = (const float*)d_in[25];
    const float* bl_b1 = (const float*)d_in[26];
    const float* bl_w2 = (const float*)d_in[27];
    const float* bl_b2 = (const float*)d_in[28];

    float* out      = (float*)d_out;
    float* out_bl   = out + 393216;
    float* out_off[2] = {out + 524288,   out + 13369344};
    float* out_wt [2] = {out + 26214400, out + 32636928};

    // workspace carve (~186 MB)
    char* ws = (char*)d_ws;
    size_t o = 0;
    auto alloc = [&](size_t bytes) { char* p = ws + o; o += (bytes + 255) & ~(size_t)255; return p; };
    unsigned short* Xc   = (unsigned short*)alloc((size_t)2 * PAD * 160 * 2);
    unsigned short* bufA = (unsigned short*)alloc((size_t)2 * PAD * 256 * 2);
    unsigned short* bufB = (unsigned short*)alloc((size_t)2 * PAD * 256 * 2);
    unsigned short *WpC1[2], *WpC2[2], *WpC3[2], *WpCo[2], *WpCw[2];
    for (int pdx = 0; pdx < 2; ++pdx) {
        WpC1[pdx] = (unsigned short*)alloc((size_t)9 * 256 * 160 * 2);
        WpC2[pdx] = (unsigned short*)alloc((size_t)9 * 256 * 256 * 2);
        WpC3[pdx] = (unsigned short*)alloc((size_t)9 * 128 * 256 * 2);
        WpCo[pdx] = (unsigned short*)alloc((size_t)9 * 128 * 128 * 2);
        WpCw[pdx] = (unsigned short*)alloc((size_t)9 * 128 * 128 * 2);
    }
    unsigned short* WpBl = (unsigned short*)alloc((size_t)9 * 128 * 160 * 2);
    f32x4* Ff = (f32x4*)bufA;   // reuse: bufA dead before sampling stage

    auto packw = [&](const float* W, unsigned short* Wp, int OC, int IC, int OCP, int ICP) {
        int total = 9 * OCP * ICP;
        pack_w<<<(total + 255) / 256, 256, 0, stream>>>(W, Wp, OC, IC, OCP, ICP / 32);
    };
    auto zb = [&](unsigned short* buf, int C) {
        int total = 2 * 1028 * (C / 8);
        zero_border<<<(total + 255) / 256, 256, 0, stream>>>(buf, C);
    };

    // stage 0: packing + border zeroing
    zb(Xc, 160);
    pack_x<<<(2 * HW * 20) / 256, 256, 0, stream>>>(feat1, feat2, corr, Xc);
    for (int pdx = 0; pdx < 2; ++pdx) {
        packw(Wsrc[pdx][0], WpC1[pdx], 256, 145, 256, 160);
        packw(Wsrc[pdx][1], WpC2[pdx], 256, 256, 256, 256);
        packw(Wsrc[pdx][2], WpC3[pdx], 128, 256, 128, 256);
        packw(Wsrc[pdx][3], WpCo[pdx],  98, 128, 128, 128);
        packw(Wsrc[pdx][4], WpCw[pdx],  49, 128, 128, 128);
    }
    packw(bl_w1, WpBl, 64, 145, 128, 160);
    zb(bufB, 256);

    // stage 1: the two predictors
    for (int pdx = 0; pdx < 2; ++pdx) {
        zb(bufA, 256);
        conv3x3<160, 256, 256, 0><<<dim3(256, 2), 512, 0, stream>>>(
            Xc, (const uint4*)WpC1[pdx], Bsrc[pdx][0], bufA, nullptr);
        conv3x3<256, 256, 256, 0><<<dim3(256, 2), 512, 0, stream>>>(
            bufA, (const uint4*)WpC2[pdx], Bsrc[pdx][1], bufB, nullptr);
        zb(bufA, 128);
        conv3x3<256, 128, 128, 0><<<dim3(256, 1), 512, 0, stream>>>(
            bufB, (const uint4*)WpC3[pdx], Bsrc[pdx][2], bufA, nullptr);
        conv3x3<128, 128, 98, 1><<<dim3(256, 1), 512, 0, stream>>>(
            bufA, (const uint4*)WpCo[pdx], Bsrc[pdx][3], nullptr, out_off[pdx]);
        conv3x3<128, 128, 49, 1><<<dim3(256, 1), 512, 0, stream>>>(
            bufA, (const uint4*)WpCw[pdx], Bsrc[pdx][4], nullptr, out_wt[pdx]);
        softmax49<<<512, 256, 0, stream>>>(out_wt[pdx]);
    }

    // stage 2: blend mask (bufB free after pdx1 conv3)
    zb(bufB, 64);
    conv3x3<160, 128, 64, 0><<<dim3(256, 1), 512, 0, stream>>>(
        Xc, (const uint4*)WpBl, bl_b1, bufB, nullptr);
    blend2k<<<512, 256, 0, stream>>>(bufB, bl_w2, bl_b2, out_bl);

    // stage 3: frame pack + deformable sampling + final blend
    pack_frames<<<(4 * HW) / 256, 256, 0, stream>>>(frame1, frame2, Ff);
    sample_final<<<512, 256, 0, stream>>>(Ff, out_off[0], out_off[1],
                                          out_wt[0], out_wt[1], out_bl, out);
}

// Round 5
// 1196.257 us; speedup vs baseline: 1.0779x; 1.0150x over previous
//
#include <hip/hip_runtime.h>

// AdaCoFNet forward on gfx950 — round 5.
// Convs: implicit-GEMM, 128oc x 512px(16x32) x 32ic, 512-thr/8-wave blocks,
// 1 block/CU @ 128 KB LDS. m201-style sub-phases: reads-BEFORE-barrier,
// lgkmcnt(0)+sched_barrier(0), setprio around 16-MFMA cluster, vmcnt gate
// only at dy-group boundaries. Activations: padded NHWC bf16 [258][258][C].

static constexpr int HW  = 65536;  // 256*256
static constexpr int WID = 256;
static constexpr int PAD = 66564;  // 258*258

using f32x16 = __attribute__((ext_vector_type(16))) float;
using f32x4  = __attribute__((ext_vector_type(4))) float;
using s16x8  = __attribute__((ext_vector_type(8))) short;

__device__ __forceinline__ unsigned short f2b(float f) {
    unsigned u = __builtin_bit_cast(unsigned, f);
    u += 0x7fffu + ((u >> 16) & 1u);          // RNE
    return (unsigned short)(u >> 16);
}
__device__ __forceinline__ float b2f(unsigned short h) {
    unsigned u = ((unsigned)h) << 16;
    return __builtin_bit_cast(float, u);
}

template <int N> __device__ __forceinline__ void vm_wait() {
    asm volatile("s_waitcnt vmcnt(%0)" :: "n"(N) : "memory");
}

// ---------------------------------------------------------------- pack_x ---
__global__ void pack_x(const float* __restrict__ feat1, const float* __restrict__ feat2,
                       const float* __restrict__ corr, unsigned short* __restrict__ Xc) {
    int idx = blockIdx.x * 256 + threadIdx.x;   // 20 groups * 2*HW pixels
    int g  = idx >> 17;
    int bp = idx & (2 * HW - 1);
    int b  = bp >> 16, p = bp & 65535;
    unsigned short v[8];
#pragma unroll
    for (int j = 0; j < 8; ++j) {
        int c = g * 8 + j;
        float val = 0.f;
        if (c < 32)       val = feat1[(size_t)(b * 32 + c) * HW + p];
        else if (c < 64)  val = feat2[(size_t)(b * 32 + (c - 32)) * HW + p];
        else if (c < 145) val = corr [(size_t)(b * 81 + (c - 64)) * HW + p];
        v[j] = f2b(val);
    }
    uint4 u;
    u.x = v[0] | ((unsigned)v[1] << 16);
    u.y = v[2] | ((unsigned)v[3] << 16);
    u.z = v[4] | ((unsigned)v[5] << 16);
    u.w = v[6] | ((unsigned)v[7] << 16);
    int y = p >> 8, x = p & 255;
    size_t cell = (size_t)b * PAD + (size_t)(y + 1) * 258 + (x + 1);
    *reinterpret_cast<uint4*>(Xc + cell * 160 + g * 8) = u;
}

// ---------------------------------------------------------------- pack_w ---
// W[OC][IC][3][3] fp32 -> granule-major bf16: Wp[((s*KC+kb)*4+g)*OCP + oc][8ic]
__global__ void pack_w(const float* __restrict__ W, unsigned short* __restrict__ Wp,
                       int OC, int IC, int OCP, int KC) {
    int idx = blockIdx.x * 256 + threadIdx.x;
    int total = 9 * KC * 4 * OCP * 8;
    if (idx >= total) return;
    int i8 = idx & 7;  int r = idx >> 3;
    int oc = r % OCP;  r /= OCP;
    int g  = r & 3;    r >>= 2;
    int kb = r % KC;   int s = r / KC;
    int ic = kb * 32 + g * 8 + i8;
    float v = (oc < OC && ic < IC) ? W[((size_t)(oc * IC + ic)) * 9 + s] : 0.f;
    Wp[idx] = f2b(v);
}

// ----------------------------------------------------------- zero_border ---
__global__ void zero_border(unsigned short* __restrict__ buf, int C) {
    int idx = blockIdx.x * 256 + threadIdx.x;
    int G = C >> 3;
    int total = 2 * 1028 * G;
    if (idx >= total) return;
    int gi = idx % G; int r = idx / G;
    int ci = r % 1028; int b = r / 1028;
    int row, col;
    if (ci < 258)      { row = 0;            col = ci; }
    else if (ci < 516) { row = 257;          col = ci - 258; }
    else if (ci < 772) { row = ci - 516 + 1; col = 0; }
    else               { row = ci - 772 + 1; col = 257; }
    *reinterpret_cast<uint4*>(buf + ((size_t)b * PAD + row * 258 + col) * C + gi * 8) =
        make_uint4(0u, 0u, 0u, 0u);
}

// ----------------------------------------------------------------- conv3x3 -
// Block: 512 thr = 8 waves (wn 0..7). Tile: 128 oc x 512 px (16 rows x 32 cols);
// blockIdx.y = 128-oc slice. Wave: 128 oc x 64 px (2 rows), acc[4][2] f32x16.
// LDS 128 KB: X dbuf 2x2560 granules ([g:4][640 cells], cell=rr*34+cc, 18x34),
//             W group-dbuf 2x1536 ([dx:3][g:4][oc:128]), slot=(kb*3+dy)&1.
// Sub-phase = one dxi: 12 ds_read_b128 -> barrier -> lgkm0 -> 16 MFMA -> barrier.
// MODE 0: +bias, lrelu, bf16 padded NHWC store. MODE 1: +bias, fp32 NCHW.
template <int ICP, int OCF, int OCT, int MODE>
__global__ __launch_bounds__(512, 2) void conv3x3(
    const unsigned short* __restrict__ X,
    const uint4* __restrict__ Wp,
    const float* __restrict__ bias,
    unsigned short* __restrict__ outB,
    float* __restrict__ outF)
{
    constexpr int KC = ICP / 32;
    __shared__ uint4 lds[8192];               // 131072 B

    const int t = threadIdx.x;
    const int lane = t & 63, wn = t >> 6;
    const int l31 = lane & 31, hi = lane >> 5;
    const int ocOff = blockIdx.y * 128;

    const int bid = blockIdx.x;               // 256 tiles (2 batches x 128)
    const int q8  = gridDim.x >> 3;
    const int work = (bid & 7) * q8 + (bid >> 3);   // XCD-bijective swizzle
    const int bb = work >> 7;
    const int tt = work & 127;
    const int tr = tt >> 3, tc = tt & 7;      // 16 row-tiles x 8 col-tiles

    auto stage_x = [&](int kb2, int slot) {
#pragma unroll
        for (int it = 0; it < 5; ++it) {
            int G = it * 512 + t;
            int g = G / 640;
            int cell = G - g * 640;
            cell = min(cell, 611);
            int rr = cell / 34, cc = cell - rr * 34;
            const unsigned short* src = X +
                ((size_t)bb * PAD + (size_t)(tr * 16 + rr) * 258 + tc * 32 + cc) * ICP +
                kb2 * 32 + g * 8;
            __builtin_amdgcn_global_load_lds(
                (const __attribute__((address_space(1))) unsigned int*)src,
                (__attribute__((address_space(3))) unsigned int*)&lds[slot * 2560 + it * 512 + (t & ~63)],
                16, 0, 0);
        }
    };
    auto stage_wg = [&](int kb2, int dy2, int wslot) {
#pragma unroll
        for (int j = 0; j < 3; ++j) {
            int s = dy2 * 3 + j;
            const uint4* src = Wp + ((size_t)(s * KC + kb2) * 4 + (t >> 7)) * OCF + ocOff + (t & 127);
            __builtin_amdgcn_global_load_lds(
                (const __attribute__((address_space(1))) unsigned int*)src,
                (__attribute__((address_space(3))) unsigned int*)&lds[5120 + wslot * 1536 + j * 512 + (t & ~63)],
                16, 0, 0);
        }
    };

    f32x16 acc[4][2] = {};

    stage_x(0, 0);
    stage_wg(0, 0, 0);
    vm_wait<0>();
    __builtin_amdgcn_s_barrier();

#pragma unroll 1
    for (int kb = 0; kb < KC; ++kb) {
        const int xb = (kb & 1) * 2560;
#pragma unroll
        for (int dy = 0; dy < 3; ++dy) {
            const int wb = 5120 + ((kb * 3 + dy) & 1) * 1536;
#pragma unroll
            for (int dxi = 0; dxi < 3; ++dxi) {
                // ---- issue LDS reads for this sub-phase (before barrier) ----
                uint4 a[2][4], bq[2][2];
#pragma unroll
                for (int ks = 0; ks < 2; ++ks) {
#pragma unroll
                    for (int fm = 0; fm < 4; ++fm)
                        a[ks][fm] = lds[wb + dxi * 512 + (ks * 2 + hi) * 128 + fm * 32 + l31];
#pragma unroll
                    for (int fn = 0; fn < 2; ++fn)
                        bq[ks][fn] = lds[xb + (ks * 2 + hi) * 640 + (wn * 2 + fn + dy) * 34 + dxi + l31];
                }
                // ---- stage prefetch (first sub-phase of each group) ----
                if (dxi == 0) {
                    if (dy == 0) {
                        stage_wg(kb, 1, (kb * 3 + 1) & 1);
                    } else if (dy == 1) {
                        stage_wg(kb, 2, (kb * 3 + 2) & 1);
                    } else if (kb + 1 < KC) {
                        stage_wg(kb + 1, 0, ((kb + 1) * 3) & 1);
                        stage_x(kb + 1, (kb + 1) & 1);
                    }
                }
                __builtin_amdgcn_s_barrier();
                asm volatile("s_waitcnt lgkmcnt(0)" ::: "memory");
                __builtin_amdgcn_sched_barrier(0);
                __builtin_amdgcn_s_setprio(1);
#pragma unroll
                for (int ks = 0; ks < 2; ++ks)
#pragma unroll
                    for (int fm = 0; fm < 4; ++fm)
#pragma unroll
                        for (int fn = 0; fn < 2; ++fn)
                            acc[fm][fn] = __builtin_amdgcn_mfma_f32_32x32x16_bf16(
                                __builtin_bit_cast(s16x8, a[ks][fm]),
                                __builtin_bit_cast(s16x8, bq[ks][fn]),
                                acc[fm][fn], 0, 0, 0);
                __builtin_amdgcn_s_setprio(0);
                if (dxi == 2) vm_wait<0>();   // gate next group's staging (issued 2 sub-phases ago)
                __builtin_amdgcn_s_barrier();
            }
        }
    }

    // epilogue: D reg -> oc_rel = fm*32 + q*8 + hi*4 + j, px col = l31
#pragma unroll
    for (int fm = 0; fm < 4; ++fm) {
#pragma unroll
        for (int fn = 0; fn < 2; ++fn) {
            const int prow = wn * 2 + fn;
            if (MODE == 0) {
                const size_t cellp = (size_t)bb * PAD + (size_t)(tr * 16 + prow + 1) * 258 + tc * 32 + l31 + 1;
#pragma unroll
                for (int qd = 0; qd < 4; ++qd) {
                    const int goc = ocOff + fm * 32 + qd * 8 + hi * 4;
                    if (goc < OCT) {
                        float4 bv = *reinterpret_cast<const float4*>(bias + goc);
                        const float* bvp = reinterpret_cast<const float*>(&bv);
                        unsigned short o[4];
#pragma unroll
                        for (int j = 0; j < 4; ++j) {
                            float r = acc[fm][fn][qd * 4 + j] + bvp[j];
                            r = (r >= 0.f) ? r : 0.1f * r;
                            o[j] = f2b(r);
                        }
                        uint2 pk;
                        pk.x = o[0] | ((unsigned)o[1] << 16);
                        pk.y = o[2] | ((unsigned)o[3] << 16);
                        *reinterpret_cast<uint2*>(outB + cellp * OCT + goc) = pk;
                    }
                }
            } else {
                const int py = tr * 16 + prow, px = tc * 32 + l31;
#pragma unroll
                for (int qd = 0; qd < 4; ++qd) {
#pragma unroll
                    for (int j = 0; j < 4; ++j) {
                        const int oc = ocOff + fm * 32 + qd * 8 + hi * 4 + j;
                        if (oc < OCT)
                            outF[((size_t)bb * OCT + oc) * HW + py * WID + px] =
                                acc[fm][fn][qd * 4 + j] + bias[oc];
                    }
                }
            }
        }
    }
}

// -------------------------------------------------------------- softmax49 --
__global__ void softmax49(float* __restrict__ L) {
    int idx = blockIdx.x * 256 + threadIdx.x;   // 2*HW
    int b = idx >> 16, p = idx & 65535;
    float* lp = L + (size_t)b * 49 * HW + p;
    float v[49];
    float mx = -1e30f;
#pragma unroll
    for (int k = 0; k < 49; ++k) { v[k] = lp[(size_t)k * HW]; mx = fmaxf(mx, v[k]); }
    float sum = 0.f;
#pragma unroll
    for (int k = 0; k < 49; ++k) { v[k] = expf(v[k] - mx); sum += v[k]; }
    float inv = 1.f / sum;
#pragma unroll
    for (int k = 0; k < 49; ++k) lp[(size_t)k * HW] = v[k] * inv;
}

// ---------------------------------------------------------------- blend2 ---
__global__ void blend2k(const unsigned short* __restrict__ Fb, const float* __restrict__ W2,
                        const float* __restrict__ B2, float* __restrict__ blendOut) {
    int idx = blockIdx.x * 256 + threadIdx.x;   // 2*HW
    int b = idx >> 16, p = idx & 65535, y = p >> 8, x = p & 255;
    float acc = B2[0];
#pragma unroll
    for (int ry = 0; ry < 3; ++ry) {
#pragma unroll
        for (int rx = 0; rx < 3; ++rx) {
            const unsigned short* fp = Fb + ((size_t)b * PAD + (size_t)(y + ry) * 258 + (x + rx)) * 64;
#pragma unroll
            for (int g = 0; g < 8; ++g) {
                uint4 u = *reinterpret_cast<const uint4*>(fp + g * 8);
                unsigned w[4] = {u.x, u.y, u.z, u.w};
#pragma unroll
                for (int h = 0; h < 4; ++h) {
                    int c = g * 8 + h * 2;
                    acc += b2f((unsigned short)(w[h] & 0xffffu)) * W2[(c)     * 9 + ry * 3 + rx];
                    acc += b2f((unsigned short)(w[h] >> 16))     * W2[(c + 1) * 9 + ry * 3 + rx];
                }
            }
        }
    }
    blendOut[idx] = 1.f / (1.f + expf(-acc));
}

// ------------------------------------------------------------ pack_frames -
__global__ void pack_frames(const float* __restrict__ f1, const float* __restrict__ f2,
                            f32x4* __restrict__ Ff) {
    int idx = blockIdx.x * 256 + threadIdx.x;   // 2 frames * 2*HW
    int fr = idx >> 17; int bp = idx & (2 * HW - 1);
    const float* src = fr ? f2 : f1;
    int b = bp >> 16, p = bp & 65535;
    f32x4 v;
    v[0] = src[(size_t)(b * 3 + 0) * HW + p];
    v[1] = src[(size_t)(b * 3 + 1) * HW + p];
    v[2] = src[(size_t)(b * 3 + 2) * HW + p];
    v[3] = 0.f;
    Ff[(size_t)fr * 2 * HW + bp] = v;
}

// ------------------------------------------------------------- sampling ----
__device__ __forceinline__ void sample_accum4(const f32x4* __restrict__ img,
                                              const float* __restrict__ off,
                                              const float* __restrict__ wt,
                                              int x, int y, f32x4& s) {
    for (int k = 0; k < 49; ++k) {
        float dx = off[(size_t)(2 * k) * HW];
        float dy = off[(size_t)(2 * k + 1) * HW];
        float w  = wt [(size_t)k * HW];
        float px = ((float)x + dx) * (256.f / 255.f) - 0.5f;
        float py = ((float)y + dy) * (256.f / 255.f) - 0.5f;
        px = fminf(fmaxf(px, 0.f), 255.f);
        py = fminf(fmaxf(py, 0.f), 255.f);
        float x0f = floorf(px), y0f = floorf(py);
        float fx = px - x0f, fy = py - y0f;
        int x0 = (int)x0f, y0 = (int)y0f;
        int x1 = min(x0 + 1, 255), y1 = min(y0 + 1, 255);
        const f32x4* r0 = img + y0 * WID;
        const f32x4* r1 = img + y1 * WID;
        f32x4 v = (1.f - fy) * ((1.f - fx) * r0[x0] + fx * r0[x1]) +
                  fy         * ((1.f - fx) * r1[x0] + fx * r1[x1]);
        s += w * v;
    }
}

__global__ void sample_final(const f32x4* __restrict__ Ff,
                             const float* __restrict__ off1, const float* __restrict__ off2,
                             const float* __restrict__ wt1, const float* __restrict__ wt2,
                             const float* __restrict__ blend, float* __restrict__ out) {
    int idx = blockIdx.x * 256 + threadIdx.x;   // 2*HW
    int b = idx >> 16, p = idx & 65535, y = p >> 8, x = p & 255;
    f32x4 s1 = {0.f, 0.f, 0.f, 0.f}, s2 = {0.f, 0.f, 0.f, 0.f};
    sample_accum4(Ff + (size_t)b * HW, off1 + (size_t)b * 98 * HW + p,
                  wt1 + (size_t)b * 49 * HW + p, x, y, s1);
    sample_accum4(Ff + (size_t)(2 + b) * HW, off2 + (size_t)b * 98 * HW + p,
                  wt2 + (size_t)b * 49 * HW + p, x, y, s2);
    float bl = blend[idx];
#pragma unroll
    for (int c = 0; c < 3; ++c)
        out[(size_t)(b * 3 + c) * HW + p] = bl * s1[c] + (1.f - bl) * s2[c];
}

// ---------------------------------------------------------------------------
extern "C" void kernel_launch(void* const* d_in, const int* in_sizes, int n_in,
                              void* d_out, int out_size, void* d_ws, size_t ws_size,
                              hipStream_t stream) {
    (void)in_sizes; (void)n_in; (void)out_size; (void)ws_size;
    const float* frame1 = (const float*)d_in[0];
    const float* frame2 = (const float*)d_in[1];
    const float* feat1  = (const float*)d_in[2];
    const float* feat2  = (const float*)d_in[3];
    const float* corr   = (const float*)d_in[4];
    const float* Wsrc[2][5];
    const float* Bsrc[2][5];
    for (int pdx = 0; pdx < 2; ++pdx) {
        int base = 5 + pdx * 10;
        for (int l = 0; l < 5; ++l) {
            Wsrc[pdx][l] = (const float*)d_in[base + 2 * l];
            Bsrc[pdx][l] = (const float*)d_in[base + 2 * l + 1];
        }
    }
    const float* bl_w1 = (const float*)d_in[25];
    const float* bl_b1 = (const float*)d_in[26];
    const float* bl_w2 = (const float*)d_in[27];
    const float* bl_b2 = (const float*)d_in[28];

    float* out      = (float*)d_out;
    float* out_bl   = out + 393216;
    float* out_off[2] = {out + 524288,   out + 13369344};
    float* out_wt [2] = {out + 26214400, out + 32636928};

    // workspace carve (~186 MB)
    char* ws = (char*)d_ws;
    size_t o = 0;
    auto alloc = [&](size_t bytes) { char* p = ws + o; o += (bytes + 255) & ~(size_t)255; return p; };
    unsigned short* Xc   = (unsigned short*)alloc((size_t)2 * PAD * 160 * 2);
    unsigned short* bufA = (unsigned short*)alloc((size_t)2 * PAD * 256 * 2);
    unsigned short* bufB = (unsigned short*)alloc((size_t)2 * PAD * 256 * 2);
    unsigned short *WpC1[2], *WpC2[2], *WpC3[2], *WpCo[2], *WpCw[2];
    for (int pdx = 0; pdx < 2; ++pdx) {
        WpC1[pdx] = (unsigned short*)alloc((size_t)9 * 256 * 160 * 2);
        WpC2[pdx] = (unsigned short*)alloc((size_t)9 * 256 * 256 * 2);
        WpC3[pdx] = (unsigned short*)alloc((size_t)9 * 128 * 256 * 2);
        WpCo[pdx] = (unsigned short*)alloc((size_t)9 * 128 * 128 * 2);
        WpCw[pdx] = (unsigned short*)alloc((size_t)9 * 128 * 128 * 2);
    }
    unsigned short* WpBl = (unsigned short*)alloc((size_t)9 * 128 * 160 * 2);
    f32x4* Ff = (f32x4*)bufA;   // reuse: bufA dead before sampling stage

    auto packw = [&](const float* W, unsigned short* Wp, int OC, int IC, int OCP, int ICP) {
        int total = 9 * OCP * ICP;
        pack_w<<<(total + 255) / 256, 256, 0, stream>>>(W, Wp, OC, IC, OCP, ICP / 32);
    };
    auto zb = [&](unsigned short* buf, int C) {
        int total = 2 * 1028 * (C / 8);
        zero_border<<<(total + 255) / 256, 256, 0, stream>>>(buf, C);
    };

    // stage 0: packing + border zeroing
    zb(Xc, 160);
    pack_x<<<(2 * HW * 20) / 256, 256, 0, stream>>>(feat1, feat2, corr, Xc);
    for (int pdx = 0; pdx < 2; ++pdx) {
        packw(Wsrc[pdx][0], WpC1[pdx], 256, 145, 256, 160);
        packw(Wsrc[pdx][1], WpC2[pdx], 256, 256, 256, 256);
        packw(Wsrc[pdx][2], WpC3[pdx], 128, 256, 128, 256);
        packw(Wsrc[pdx][3], WpCo[pdx],  98, 128, 128, 128);
        packw(Wsrc[pdx][4], WpCw[pdx],  49, 128, 128, 128);
    }
    packw(bl_w1, WpBl, 64, 145, 128, 160);
    zb(bufB, 256);

    // stage 1: the two predictors
    for (int pdx = 0; pdx < 2; ++pdx) {
        zb(bufA, 256);
        conv3x3<160, 256, 256, 0><<<dim3(256, 2), 512, 0, stream>>>(
            Xc, (const uint4*)WpC1[pdx], Bsrc[pdx][0], bufA, nullptr);
        conv3x3<256, 256, 256, 0><<<dim3(256, 2), 512, 0, stream>>>(
            bufA, (const uint4*)WpC2[pdx], Bsrc[pdx][1], bufB, nullptr);
        zb(bufA, 128);
        conv3x3<256, 128, 128, 0><<<dim3(256, 1), 512, 0, stream>>>(
            bufB, (const uint4*)WpC3[pdx], Bsrc[pdx][2], bufA, nullptr);
        conv3x3<128, 128, 98, 1><<<dim3(256, 1), 512, 0, stream>>>(
            bufA, (const uint4*)WpCo[pdx], Bsrc[pdx][3], nullptr, out_off[pdx]);
        conv3x3<128, 128, 49, 1><<<dim3(256, 1), 512, 0, stream>>>(
            bufA, (const uint4*)WpCw[pdx], Bsrc[pdx][4], nullptr, out_wt[pdx]);
        softmax49<<<512, 256, 0, stream>>>(out_wt[pdx]);
    }

    // stage 2: blend mask (bufB free after pdx1 conv3)
    zb(bufB, 64);
    conv3x3<160, 128, 64, 0><<<dim3(256, 1), 512, 0, stream>>>(
        Xc, (const uint4*)WpBl, bl_b1, bufB, nullptr);
    blend2k<<<512, 256, 0, stream>>>(bufB, bl_w2, bl_b2, out_bl);

    // stage 3: frame pack + deformable sampling + final blend
    pack_frames<<<(4 * HW) / 256, 256, 0, stream>>>(frame1, frame2, Ff);
    sample_final<<<512, 256, 0, stream>>>(Ff, out_off[0], out_off[1],
                                          out_wt[0], out_wt[1], out_bl, out);
}

// Round 6
// 1190.235 us; speedup vs baseline: 1.0833x; 1.0051x over previous
//
#include <hip/hip_runtime.h>

// AdaCoFNet forward on gfx950 — round 6.
// Convs: implicit-GEMM, 128oc x 512px(16x32) x 32ic, 512-thr/8-wave blocks,
// 1 block/CU @ 128 KB LDS. Barrier-LIGHT schedule: ONE s_barrier + one counted
// vm_wait per dy-group (3 dx shifts, 36 ds_read + 48 MFMA per wave); compiler
// auto-lgkmcnt interleaves reads under MFMAs, waves drift for pipe overlap.
// Activations: padded NHWC bf16 [258][258][C].

static constexpr int HW  = 65536;  // 256*256
static constexpr int WID = 256;
static constexpr int PAD = 66564;  // 258*258

using f32x16 = __attribute__((ext_vector_type(16))) float;
using f32x4  = __attribute__((ext_vector_type(4))) float;
using s16x8  = __attribute__((ext_vector_type(8))) short;

__device__ __forceinline__ unsigned short f2b(float f) {
    unsigned u = __builtin_bit_cast(unsigned, f);
    u += 0x7fffu + ((u >> 16) & 1u);          // RNE
    return (unsigned short)(u >> 16);
}
__device__ __forceinline__ float b2f(unsigned short h) {
    unsigned u = ((unsigned)h) << 16;
    return __builtin_bit_cast(float, u);
}

template <int N> __device__ __forceinline__ void vm_wait() {
    asm volatile("s_waitcnt vmcnt(%0)" :: "n"(N) : "memory");
}

// ---------------------------------------------------------------- pack_x ---
__global__ void pack_x(const float* __restrict__ feat1, const float* __restrict__ feat2,
                       const float* __restrict__ corr, unsigned short* __restrict__ Xc) {
    int idx = blockIdx.x * 256 + threadIdx.x;   // 20 groups * 2*HW pixels
    int g  = idx >> 17;
    int bp = idx & (2 * HW - 1);
    int b  = bp >> 16, p = bp & 65535;
    unsigned short v[8];
#pragma unroll
    for (int j = 0; j < 8; ++j) {
        int c = g * 8 + j;
        float val = 0.f;
        if (c < 32)       val = feat1[(size_t)(b * 32 + c) * HW + p];
        else if (c < 64)  val = feat2[(size_t)(b * 32 + (c - 32)) * HW + p];
        else if (c < 145) val = corr [(size_t)(b * 81 + (c - 64)) * HW + p];
        v[j] = f2b(val);
    }
    uint4 u;
    u.x = v[0] | ((unsigned)v[1] << 16);
    u.y = v[2] | ((unsigned)v[3] << 16);
    u.z = v[4] | ((unsigned)v[5] << 16);
    u.w = v[6] | ((unsigned)v[7] << 16);
    int y = p >> 8, x = p & 255;
    size_t cell = (size_t)b * PAD + (size_t)(y + 1) * 258 + (x + 1);
    *reinterpret_cast<uint4*>(Xc + cell * 160 + g * 8) = u;
}

// ---------------------------------------------------------------- pack_w ---
// W[OC][IC][3][3] fp32 -> granule-major bf16: Wp[((s*KC+kb)*4+g)*OCP + oc][8ic]
__global__ void pack_w(const float* __restrict__ W, unsigned short* __restrict__ Wp,
                       int OC, int IC, int OCP, int KC) {
    int idx = blockIdx.x * 256 + threadIdx.x;
    int total = 9 * KC * 4 * OCP * 8;
    if (idx >= total) return;
    int i8 = idx & 7;  int r = idx >> 3;
    int oc = r % OCP;  r /= OCP;
    int g  = r & 3;    r >>= 2;
    int kb = r % KC;   int s = r / KC;
    int ic = kb * 32 + g * 8 + i8;
    float v = (oc < OC && ic < IC) ? W[((size_t)(oc * IC + ic)) * 9 + s] : 0.f;
    Wp[idx] = f2b(v);
}

// ----------------------------------------------------------- zero_border ---
__global__ void zero_border(unsigned short* __restrict__ buf, int C) {
    int idx = blockIdx.x * 256 + threadIdx.x;
    int G = C >> 3;
    int total = 2 * 1028 * G;
    if (idx >= total) return;
    int gi = idx % G; int r = idx / G;
    int ci = r % 1028; int b = r / 1028;
    int row, col;
    if (ci < 258)      { row = 0;            col = ci; }
    else if (ci < 516) { row = 257;          col = ci - 258; }
    else if (ci < 772) { row = ci - 516 + 1; col = 0; }
    else               { row = ci - 772 + 1; col = 257; }
    *reinterpret_cast<uint4*>(buf + ((size_t)b * PAD + row * 258 + col) * C + gi * 8) =
        make_uint4(0u, 0u, 0u, 0u);
}

// ----------------------------------------------------------------- conv3x3 -
// Block: 512 thr = 8 waves (wn 0..7). Tile: 128 oc x 512 px (16 rows x 32 cols);
// blockIdx.y = 128-oc slice. Wave: 128 oc x 64 px (2 rows), acc[4][2] f32x16.
// LDS 128 KB: X dbuf 2x2560 granules ([g:4][640 cells], cell=rr*34+cc, 18x34),
//             W group-dbuf 2x1536 ([dx:3][g:4][oc:128]), slot=(kb*3+dy)&1.
// Per dy-group: barrier -> stage prefetch -> counted vm_wait -> 3x{12 ds_read
// + 16 MFMA} with NO internal barriers (compiler lgkmcnt + wave drift).
// MODE 0: +bias, lrelu, bf16 padded NHWC store. MODE 1: +bias, fp32 NCHW.
template <int ICP, int OCF, int OCT, int MODE>
__global__ __launch_bounds__(512, 2) void conv3x3(
    const unsigned short* __restrict__ X,
    const uint4* __restrict__ Wp,
    const float* __restrict__ bias,
    unsigned short* __restrict__ outB,
    float* __restrict__ outF)
{
    constexpr int KC = ICP / 32;
    __shared__ uint4 lds[8192];               // 131072 B

    const int t = threadIdx.x;
    const int lane = t & 63, wn = t >> 6;
    const int l31 = lane & 31, hi = lane >> 5;
    const int ocOff = blockIdx.y * 128;

    const int bid = blockIdx.x;               // 256 tiles (2 batches x 128)
    const int q8  = gridDim.x >> 3;
    const int work = (bid & 7) * q8 + (bid >> 3);   // XCD-bijective swizzle
    const int bb = work >> 7;
    const int tt = work & 127;
    const int tr = tt >> 3, tc = tt & 7;      // 16 row-tiles x 8 col-tiles

    auto stage_x = [&](int kb2, int slot) {
#pragma unroll
        for (int it = 0; it < 5; ++it) {
            int G = it * 512 + t;
            int g = G / 640;
            int cell = G - g * 640;
            cell = min(cell, 611);
            int rr = cell / 34, cc = cell - rr * 34;
            const unsigned short* src = X +
                ((size_t)bb * PAD + (size_t)(tr * 16 + rr) * 258 + tc * 32 + cc) * ICP +
                kb2 * 32 + g * 8;
            __builtin_amdgcn_global_load_lds(
                (const __attribute__((address_space(1))) unsigned int*)src,
                (__attribute__((address_space(3))) unsigned int*)&lds[slot * 2560 + it * 512 + (t & ~63)],
                16, 0, 0);
        }
    };
    auto stage_wg = [&](int kb2, int dy2, int wslot) {
#pragma unroll
        for (int j = 0; j < 3; ++j) {
            int s = dy2 * 3 + j;
            const uint4* src = Wp + ((size_t)(s * KC + kb2) * 4 + (t >> 7)) * OCF + ocOff + (t & 127);
            __builtin_amdgcn_global_load_lds(
                (const __attribute__((address_space(1))) unsigned int*)src,
                (__attribute__((address_space(3))) unsigned int*)&lds[5120 + wslot * 1536 + j * 512 + (t & ~63)],
                16, 0, 0);
        }
    };

    f32x16 acc[4][2] = {};

    stage_x(0, 0);
    stage_wg(0, 0, 0);

#pragma unroll 1
    for (int kb = 0; kb < KC; ++kb) {
        const int xb = (kb & 1) * 2560;
#pragma unroll
        for (int dy = 0; dy < 3; ++dy) {
            const int wb = 5120 + ((kb * 3 + dy) & 1) * 1536;
            // -------- group entry: one barrier, stage prefetch, counted wait
            __builtin_amdgcn_s_barrier();
            const bool lastG = (kb == KC - 1) && (dy == 2);
            if (dy == 0) {
                stage_wg(kb, 1, (kb * 3 + 1) & 1);
            } else if (dy == 1) {
                stage_wg(kb, 2, (kb * 3 + 2) & 1);
            } else if (kb + 1 < KC) {
                stage_wg(kb + 1, 0, (3 * (kb + 1)) & 1);
                stage_x(kb + 1, (kb + 1) & 1);
            }
            if (lastG)        vm_wait<0>();
            else if (dy == 2) vm_wait<8>();
            else              vm_wait<3>();

            // -------- 3 dx sub-blocks, NO internal barriers
#pragma unroll
            for (int dxi = 0; dxi < 3; ++dxi) {
                uint4 a[2][4], bq[2][2];
#pragma unroll
                for (int ks = 0; ks < 2; ++ks) {
#pragma unroll
                    for (int fm = 0; fm < 4; ++fm)
                        a[ks][fm] = lds[wb + dxi * 512 + (ks * 2 + hi) * 128 + fm * 32 + l31];
#pragma unroll
                    for (int fn = 0; fn < 2; ++fn)
                        bq[ks][fn] = lds[xb + (ks * 2 + hi) * 640 + (wn * 2 + fn + dy) * 34 + dxi + l31];
                }
                __builtin_amdgcn_s_setprio(1);
#pragma unroll
                for (int ks = 0; ks < 2; ++ks)
#pragma unroll
                    for (int fm = 0; fm < 4; ++fm)
#pragma unroll
                        for (int fn = 0; fn < 2; ++fn)
                            acc[fm][fn] = __builtin_amdgcn_mfma_f32_32x32x16_bf16(
                                __builtin_bit_cast(s16x8, a[ks][fm]),
                                __builtin_bit_cast(s16x8, bq[ks][fn]),
                                acc[fm][fn], 0, 0, 0);
                __builtin_amdgcn_s_setprio(0);
            }
        }
    }

    // epilogue: D reg -> oc_rel = fm*32 + q*8 + hi*4 + j, px col = l31
#pragma unroll
    for (int fm = 0; fm < 4; ++fm) {
#pragma unroll
        for (int fn = 0; fn < 2; ++fn) {
            const int prow = wn * 2 + fn;
            if (MODE == 0) {
                const size_t cellp = (size_t)bb * PAD + (size_t)(tr * 16 + prow + 1) * 258 + tc * 32 + l31 + 1;
#pragma unroll
                for (int qd = 0; qd < 4; ++qd) {
                    const int goc = ocOff + fm * 32 + qd * 8 + hi * 4;
                    if (goc < OCT) {
                        float4 bv = *reinterpret_cast<const float4*>(bias + goc);
                        const float* bvp = reinterpret_cast<const float*>(&bv);
                        unsigned short o[4];
#pragma unroll
                        for (int j = 0; j < 4; ++j) {
                            float r = acc[fm][fn][qd * 4 + j] + bvp[j];
                            r = (r >= 0.f) ? r : 0.1f * r;
                            o[j] = f2b(r);
                        }
                        uint2 pk;
                        pk.x = o[0] | ((unsigned)o[1] << 16);
                        pk.y = o[2] | ((unsigned)o[3] << 16);
                        *reinterpret_cast<uint2*>(outB + cellp * OCT + goc) = pk;
                    }
                }
            } else {
                const int py = tr * 16 + prow, px = tc * 32 + l31;
#pragma unroll
                for (int qd = 0; qd < 4; ++qd) {
#pragma unroll
                    for (int j = 0; j < 4; ++j) {
                        const int oc = ocOff + fm * 32 + qd * 8 + hi * 4 + j;
                        if (oc < OCT)
                            outF[((size_t)bb * OCT + oc) * HW + py * WID + px] =
                                acc[fm][fn][qd * 4 + j] + bias[oc];
                    }
                }
            }
        }
    }
}

// -------------------------------------------------------------- softmax49 --
__global__ void softmax49(float* __restrict__ L) {
    int idx = blockIdx.x * 256 + threadIdx.x;   // 2*HW
    int b = idx >> 16, p = idx & 65535;
    float* lp = L + (size_t)b * 49 * HW + p;
    float v[49];
    float mx = -1e30f;
#pragma unroll
    for (int k = 0; k < 49; ++k) { v[k] = lp[(size_t)k * HW]; mx = fmaxf(mx, v[k]); }
    float sum = 0.f;
#pragma unroll
    for (int k = 0; k < 49; ++k) { v[k] = expf(v[k] - mx); sum += v[k]; }
    float inv = 1.f / sum;
#pragma unroll
    for (int k = 0; k < 49; ++k) lp[(size_t)k * HW] = v[k] * inv;
}

// ---------------------------------------------------------------- blend2 ---
__global__ void blend2k(const unsigned short* __restrict__ Fb, const float* __restrict__ W2,
                        const float* __restrict__ B2, float* __restrict__ blendOut) {
    int idx = blockIdx.x * 256 + threadIdx.x;   // 2*HW
    int b = idx >> 16, p = idx & 65535, y = p >> 8, x = p & 255;
    float acc = B2[0];
#pragma unroll
    for (int ry = 0; ry < 3; ++ry) {
#pragma unroll
        for (int rx = 0; rx < 3; ++rx) {
            const unsigned short* fp = Fb + ((size_t)b * PAD + (size_t)(y + ry) * 258 + (x + rx)) * 64;
#pragma unroll
            for (int g = 0; g < 8; ++g) {
                uint4 u = *reinterpret_cast<const uint4*>(fp + g * 8);
                unsigned w[4] = {u.x, u.y, u.z, u.w};
#pragma unroll
                for (int h = 0; h < 4; ++h) {
                    int c = g * 8 + h * 2;
                    acc += b2f((unsigned short)(w[h] & 0xffffu)) * W2[(c)     * 9 + ry * 3 + rx];
                    acc += b2f((unsigned short)(w[h] >> 16))     * W2[(c + 1) * 9 + ry * 3 + rx];
                }
            }
        }
    }
    blendOut[idx] = 1.f / (1.f + expf(-acc));
}

// ------------------------------------------------------------ pack_frames -
__global__ void pack_frames(const float* __restrict__ f1, const float* __restrict__ f2,
                            f32x4* __restrict__ Ff) {
    int idx = blockIdx.x * 256 + threadIdx.x;   // 2 frames * 2*HW
    int fr = idx >> 17; int bp = idx & (2 * HW - 1);
    const float* src = fr ? f2 : f1;
    int b = bp >> 16, p = bp & 65535;
    f32x4 v;
    v[0] = src[(size_t)(b * 3 + 0) * HW + p];
    v[1] = src[(size_t)(b * 3 + 1) * HW + p];
    v[2] = src[(size_t)(b * 3 + 2) * HW + p];
    v[3] = 0.f;
    Ff[(size_t)fr * 2 * HW + bp] = v;
}

// ------------------------------------------------------------- sampling ----
__device__ __forceinline__ void sample_accum4(const f32x4* __restrict__ img,
                                              const float* __restrict__ off,
                                              const float* __restrict__ wt,
                                              int x, int y, f32x4& s) {
    for (int k = 0; k < 49; ++k) {
        float dx = off[(size_t)(2 * k) * HW];
        float dy = off[(size_t)(2 * k + 1) * HW];
        float w  = wt [(size_t)k * HW];
        float px = ((float)x + dx) * (256.f / 255.f) - 0.5f;
        float py = ((float)y + dy) * (256.f / 255.f) - 0.5f;
        px = fminf(fmaxf(px, 0.f), 255.f);
        py = fminf(fmaxf(py, 0.f), 255.f);
        float x0f = floorf(px), y0f = floorf(py);
        float fx = px - x0f, fy = py - y0f;
        int x0 = (int)x0f, y0 = (int)y0f;
        int x1 = min(x0 + 1, 255), y1 = min(y0 + 1, 255);
        const f32x4* r0 = img + y0 * WID;
        const f32x4* r1 = img + y1 * WID;
        f32x4 v = (1.f - fy) * ((1.f - fx) * r0[x0] + fx * r0[x1]) +
                  fy         * ((1.f - fx) * r1[x0] + fx * r1[x1]);
        s += w * v;
    }
}

__global__ void sample_final(const f32x4* __restrict__ Ff,
                             const float* __restrict__ off1, const float* __restrict__ off2,
                             const float* __restrict__ wt1, const float* __restrict__ wt2,
                             const float* __restrict__ blend, float* __restrict__ out) {
    int idx = blockIdx.x * 256 + threadIdx.x;   // 2*HW
    int b = idx >> 16, p = idx & 65535, y = p >> 8, x = p & 255;
    f32x4 s1 = {0.f, 0.f, 0.f, 0.f}, s2 = {0.f, 0.f, 0.f, 0.f};
    sample_accum4(Ff + (size_t)b * HW, off1 + (size_t)b * 98 * HW + p,
                  wt1 + (size_t)b * 49 * HW + p, x, y, s1);
    sample_accum4(Ff + (size_t)(2 + b) * HW, off2 + (size_t)b * 98 * HW + p,
                  wt2 + (size_t)b * 49 * HW + p, x, y, s2);
    float bl = blend[idx];
#pragma unroll
    for (int c = 0; c < 3; ++c)
        out[(size_t)(b * 3 + c) * HW + p] = bl * s1[c] + (1.f - bl) * s2[c];
}

// ---------------------------------------------------------------------------
extern "C" void kernel_launch(void* const* d_in, const int* in_sizes, int n_in,
                              void* d_out, int out_size, void* d_ws, size_t ws_size,
                              hipStream_t stream) {
    (void)in_sizes; (void)n_in; (void)out_size; (void)ws_size;
    const float* frame1 = (const float*)d_in[0];
    const float* frame2 = (const float*)d_in[1];
    const float* feat1  = (const float*)d_in[2];
    const float* feat2  = (const float*)d_in[3];
    const float* corr   = (const float*)d_in[4];
    const float* Wsrc[2][5];
    const float* Bsrc[2][5];
    for (int pdx = 0; pdx < 2; ++pdx) {
        int base = 5 + pdx * 10;
        for (int l = 0; l < 5; ++l) {
            Wsrc[pdx][l] = (const float*)d_in[base + 2 * l];
            Bsrc[pdx][l] = (const float*)d_in[base + 2 * l + 1];
        }
    }
    const float* bl_w1 = (const float*)d_in[25];
    const float* bl_b1 = (const float*)d_in[26];
    const float* bl_w2 = (const float*)d_in[27];
    const float* bl_b2 = (const float*)d_in[28];

    float* out      = (float*)d_out;
    float* out_bl   = out + 393216;
    float* out_off[2] = {out + 524288,   out + 13369344};
    float* out_wt [2] = {out + 26214400, out + 32636928};

    // workspace carve (~186 MB)
    char* ws = (char*)d_ws;
    size_t o = 0;
    auto alloc = [&](size_t bytes) { char* p = ws + o; o += (bytes + 255) & ~(size_t)255; return p; };
    unsigned short* Xc   = (unsigned short*)alloc((size_t)2 * PAD * 160 * 2);
    unsigned short* bufA = (unsigned short*)alloc((size_t)2 * PAD * 256 * 2);
    unsigned short* bufB = (unsigned short*)alloc((size_t)2 * PAD * 256 * 2);
    unsigned short *WpC1[2], *WpC2[2], *WpC3[2], *WpCo[2], *WpCw[2];
    for (int pdx = 0; pdx < 2; ++pdx) {
        WpC1[pdx] = (unsigned short*)alloc((size_t)9 * 256 * 160 * 2);
        WpC2[pdx] = (unsigned short*)alloc((size_t)9 * 256 * 256 * 2);
        WpC3[pdx] = (unsigned short*)alloc((size_t)9 * 128 * 256 * 2);
        WpCo[pdx] = (unsigned short*)alloc((size_t)9 * 128 * 128 * 2);
        WpCw[pdx] = (unsigned short*)alloc((size_t)9 * 128 * 128 * 2);
    }
    unsigned short* WpBl = (unsigned short*)alloc((size_t)9 * 128 * 160 * 2);
    f32x4* Ff = (f32x4*)bufA;   // reuse: bufA dead before sampling stage

    auto packw = [&](const float* W, unsigned short* Wp, int OC, int IC, int OCP, int ICP) {
        int total = 9 * OCP * ICP;
        pack_w<<<(total + 255) / 256, 256, 0, stream>>>(W, Wp, OC, IC, OCP, ICP / 32);
    };
    auto zb = [&](unsigned short* buf, int C) {
        int total = 2 * 1028 * (C / 8);
        zero_border<<<(total + 255) / 256, 256, 0, stream>>>(buf, C);
    };

    // stage 0: packing + border zeroing
    zb(Xc, 160);
    pack_x<<<(2 * HW * 20) / 256, 256, 0, stream>>>(feat1, feat2, corr, Xc);
    for (int pdx = 0; pdx < 2; ++pdx) {
        packw(Wsrc[pdx][0], WpC1[pdx], 256, 145, 256, 160);
        packw(Wsrc[pdx][1], WpC2[pdx], 256, 256, 256, 256);
        packw(Wsrc[pdx][2], WpC3[pdx], 128, 256, 128, 256);
        packw(Wsrc[pdx][3], WpCo[pdx],  98, 128, 128, 128);
        packw(Wsrc[pdx][4], WpCw[pdx],  49, 128, 128, 128);
    }
    packw(bl_w1, WpBl, 64, 145, 128, 160);
    zb(bufB, 256);

    // stage 1: the two predictors
    for (int pdx = 0; pdx < 2; ++pdx) {
        zb(bufA, 256);
        conv3x3<160, 256, 256, 0><<<dim3(256, 2), 512, 0, stream>>>(
            Xc, (const uint4*)WpC1[pdx], Bsrc[pdx][0], bufA, nullptr);
        conv3x3<256, 256, 256, 0><<<dim3(256, 2), 512, 0, stream>>>(
            bufA, (const uint4*)WpC2[pdx], Bsrc[pdx][1], bufB, nullptr);
        zb(bufA, 128);
        conv3x3<256, 128, 128, 0><<<dim3(256, 1), 512, 0, stream>>>(
            bufB, (const uint4*)WpC3[pdx], Bsrc[pdx][2], bufA, nullptr);
        conv3x3<128, 128, 98, 1><<<dim3(256, 1), 512, 0, stream>>>(
            bufA, (const uint4*)WpCo[pdx], Bsrc[pdx][3], nullptr, out_off[pdx]);
        conv3x3<128, 128, 49, 1><<<dim3(256, 1), 512, 0, stream>>>(
            bufA, (const uint4*)WpCw[pdx], Bsrc[pdx][4], nullptr, out_wt[pdx]);
        softmax49<<<512, 256, 0, stream>>>(out_wt[pdx]);
    }

    // stage 2: blend mask (bufB free after pdx1 conv3)
    zb(bufB, 64);
    conv3x3<160, 128, 64, 0><<<dim3(256, 1), 512, 0, stream>>>(
        Xc, (const uint4*)WpBl, bl_b1, bufB, nullptr);
    blend2k<<<512, 256, 0, stream>>>(bufB, bl_w2, bl_b2, out_bl);

    // stage 3: frame pack + deformable sampling + final blend
    pack_frames<<<(4 * HW) / 256, 256, 0, stream>>>(frame1, frame2, Ff);
    sample_final<<<512, 256, 0, stream>>>(Ff, out_off[0], out_off[1],
                                          out_wt[0], out_wt[1], out_bl, out);
}